// Round 1
// baseline (8485.898 us; speedup 1.0000x reference)
//
#include <hip/hip_runtime.h>

// AugmentedLstm: B=16, T=2048, D=H=512.
// 64 persistent WGs x 256 threads. No grid barrier: h' published as packed
// u64 agent-scope relaxed atomics {2 x f16, u32 step-tag}; consumers poll
// tags. Round 4: FLAG-GATED polling. Theory: agent-scope atomic loads are
// L2-bypassing (FETCH_SIZE ~678MB has no room for hex refills), so every
// re-poll round was a full 32KB/WG IC round trip (4096 atomic ops). Now:
// each thread's 16 polled u64s come from exactly ONE publisher WG, so the
// wait loop reads just 2 per-publisher-wave hint flags (16x less IC traffic
// per round); the tagged data is fetched ~once and verified via embedded
// tags (ground truth — flags are only a hint, relaxed-store races are
// absorbed by the consumer's own fetch latency and caught by the retry).
// Speculative early data issue preserves the straggler fast path.
//
// Math: g = (x_t + h)@Wt[:, :5H] + 2b  (pi and ps share W)
//       pi5 = (x+h)@W5 - h@W5 + b5     (highway input)

#define NG 64
#define BLK 256
#define BB 16
#define TT 2048
#define DD 512
#define HHH 512
#define CC 8

typedef _Float16 f16;
typedef _Float16 f16x4 __attribute__((ext_vector_type(4)));
typedef _Float16 f16x8 __attribute__((ext_vector_type(8)));
typedef float f32x4 __attribute__((ext_vector_type(4)));
typedef unsigned long long u64;

__device__ __forceinline__ float sigf(float v) {
  return 1.0f / (1.0f + __expf(-v));
}
__device__ __forceinline__ float tanhfast(float v) {
  return 2.0f / (1.0f + __expf(-2.0f * v)) - 1.0f;
}

__device__ __forceinline__ f16 h_lo(u64 w) {
  return __builtin_bit_cast(f16, (unsigned short)(w & 0xffffu));
}
__device__ __forceinline__ f16 h_hi(u64 w) {
  return __builtin_bit_cast(f16, (unsigned short)((w >> 16) & 0xffffu));
}

__global__ __launch_bounds__(BLK, 1) void lstm_scan(
    const float* __restrict__ x, const int* __restrict__ lengths,
    const float* __restrict__ W, const float* __restrict__ bias,
    float* __restrict__ out,
    u64* __restrict__ hex /* [2][16][256] tagged pairs + [128] flags */) {
  __shared__ f16 u_sw[BB * DD];        // u = x+h, swizzled A-frag order
  __shared__ f16 h_sw[BB * DD];        // h alone (for h@W5)
  __shared__ float gbuf[4 * 16 * 17];  // per-tile MFMA results
  __shared__ float cbuf[BB * CC];      // cell state

  const int tid = threadIdx.x;
  const int wg = blockIdx.x;
  const int wave = tid >> 6;
  const int lane = tid & 63;
  const int q = lane >> 4;
  const int n16 = lane & 15;

  // ---- Weight B-fragments in registers (loaded once).
  // Tiles 0..2: A=u, 16 cols = gates {0,1},{2,3},{4,5} x 8 cols.
  // Tile  3   : A=h, cols 0..7 = gate-5 rows (h@W5), cols 8..15 zero.
  f16x8 bW[16];
  {
    int grow = 0;
    bool valid = true;
    if (wave < 3) {
      int gate = 2 * wave + (n16 >> 3);
      grow = gate * HHH + wg * CC + (n16 & 7);
    } else if (n16 < 8) {
      grow = 5 * HHH + wg * CC + n16;
    } else {
      valid = false;
    }
    const float* wr = W + (size_t)grow * DD;
#pragma unroll
    for (int kk = 0; kk < 16; ++kk) {
      f16x8 v;
      if (valid) {
        const float* p = wr + kk * 32 + q * 8;
#pragma unroll
        for (int j = 0; j < 8; ++j) v[j] = (f16)p[j];
      } else {
#pragma unroll
        for (int j = 0; j < 8; ++j) v[j] = (f16)0.0f;
      }
      bW[kk] = v;
    }
  }

  // ---- Staging indices. Thread's i-th chunk = cols k..k+3 of row m of the
  // flat [16][512] matrix. LDS granule (8 f16): logical (kk*64 + L),
  // physical (kk*64 + (L ^ kk)) — XOR swizzle keeps ds_write at the 4-way
  // floor and ds_read_b128 conflict-free.
  int soffv[8], pidx[8];
  size_t xcm[8];
#pragma unroll
  for (int i = 0; i < 8; ++i) {
    int e = (tid + i * BLK) * 4;
    int m = e >> 9;
    int k = e & 511;
    pidx[i] = m * 256 + (k >> 1);      // u64 pair index (k multiple of 4)
    xcm[i] = (size_t)m * TT * DD + k;  // x[b=m][t][k] base
    int kk = k >> 5, qq = (k >> 3) & 3, j0 = k & 7;
    int L = qq * 16 + m;
    soffv[i] = (kk * 64 + (L ^ kk)) * 8 + j0;
  }

  // ---- Flag pointers. Thread's 8 chunks all have k0 = (tid*4)&511, i.e.
  // all 16 polled u64s come from publisher WG wgp = k0>>3, rows of parity
  // tid>>7 (both publishing waves) → gate on that WG's 2 per-wave flags.
  // Flags are 64B-strided monotonic step counters (hint only; embedded
  // tags in the data remain the ground truth).
  u64* const flg = hex + 8192;
  const int wgp = ((tid * 4) & 511) >> 3;
  const u64* fp0 = flg + ((size_t)wgp * 2 + 0) * 8;
  const u64* fp1 = flg + ((size_t)wgp * 2 + 1) * 8;

  // ---- Epilogue constants (threads 0..127: b = tid>>3, n = tid&7).
  const int eb = tid >> 3;
  const int en = tid & 7;
  float bb0 = 0, bb1 = 0, bb2 = 0, bb3 = 0, bb4 = 0, bb5 = 0;
  int mylen = 0;
  if (tid < 128) {
    int gc = wg * CC + en;
    bb0 = bias[0 * HHH + gc];
    bb1 = bias[1 * HHH + gc];
    bb2 = bias[2 * HHH + gc];
    bb3 = bias[3 * HHH + gc];
    bb4 = bias[4 * HHH + gc];
    bb5 = bias[5 * HHH + gc];
    mylen = lengths[eb];
    cbuf[tid] = 0.0f;
  }

  // Prefetch x(t=0).
  f32x4 xv[8];
#pragma unroll
  for (int i = 0; i < 8; ++i) xv[i] = *(const f32x4*)(x + xcm[i]);

  __syncthreads();

  for (int t = 0; t < TT; ++t) {
    const u64* hb = hex + (size_t)(t & 1) * 4096;
    const unsigned wtag = (unsigned)t;
    const u64 ftag = (u64)t;
    u64 w0[8], w1[8];

    // ---- Speculative data issue: if our publisher finished long ago
    // (we're the straggler), these return fresh and the verify below
    // passes with zero extra IC hops.
#pragma unroll
    for (int i = 0; i < 8; ++i) {
      w0[i] = __hip_atomic_load(hb + pidx[i], __ATOMIC_RELAXED,
                                __HIP_MEMORY_SCOPE_AGENT);
      w1[i] = __hip_atomic_load(hb + pidx[i] + 1, __ATOMIC_RELAXED,
                                __HIP_MEMORY_SCOPE_AGENT);
    }

    // ---- Cheap flag gate: 2 IC loads per round (was 16 full-data loads).
    // Publisher wrote flag = t at its step t-1 epilogue; it can run at
    // most one step ahead (flag = t+1), so >= is the correct test.
    for (;;) {
      u64 fa = __hip_atomic_load(fp0, __ATOMIC_RELAXED,
                                 __HIP_MEMORY_SCOPE_AGENT);
      u64 fb = __hip_atomic_load(fp1, __ATOMIC_RELAXED,
                                 __HIP_MEMORY_SCOPE_AGENT);
      if (fa >= ftag && fb >= ftag) break;
    }

    // ---- Verify embedded tags; reload on failure (typically 0-1 reloads:
    // flag and pair stores issue back-to-back in the publisher wave, and
    // our reload's own >=700cy fetch latency absorbs any commit skew).
    for (;;) {
      unsigned bad = 0;
#pragma unroll
      for (int i = 0; i < 8; ++i)
        bad |= ((unsigned)(w0[i] >> 32) ^ wtag) |
               ((unsigned)(w1[i] >> 32) ^ wtag);
      if (bad == 0) break;
#pragma unroll
      for (int i = 0; i < 8; ++i) {
        w0[i] = __hip_atomic_load(hb + pidx[i], __ATOMIC_RELAXED,
                                  __HIP_MEMORY_SCOPE_AGENT);
        w1[i] = __hip_atomic_load(hb + pidx[i] + 1, __ATOMIC_RELAXED,
                                  __HIP_MEMORY_SCOPE_AGENT);
      }
    }

    // ---- Stage u = f16(x)+h and h into LDS (swizzled).
#pragma unroll
    for (int i = 0; i < 8; ++i) {
      f16x4 hv;
      hv[0] = h_lo(w0[i]);
      hv[1] = h_hi(w0[i]);
      hv[2] = h_lo(w1[i]);
      hv[3] = h_hi(w1[i]);
      f16x4 uv;
#pragma unroll
      for (int j = 0; j < 4; ++j) uv[j] = (f16)xv[i][j] + hv[j];
      *(f16x4*)(u_sw + soffv[i]) = uv;
      *(f16x4*)(h_sw + soffv[i]) = hv;
    }
    __syncthreads();

    // ---- MFMA: wave's 16-col tile, K=512, 4 independent chains.
    f32x4 acc0 = {0.f, 0.f, 0.f, 0.f}, acc1 = {0.f, 0.f, 0.f, 0.f};
    f32x4 acc2 = {0.f, 0.f, 0.f, 0.f}, acc3 = {0.f, 0.f, 0.f, 0.f};
    const f16* asrc = (wave < 3) ? u_sw : h_sw;
#pragma unroll
    for (int kk = 0; kk < 16; kk += 4) {
      f16x8 a0 = *(const f16x8*)(asrc + (kk * 64 + (lane ^ kk)) * 8);
      f16x8 a1 =
          *(const f16x8*)(asrc + ((kk + 1) * 64 + (lane ^ (kk + 1))) * 8);
      f16x8 a2 =
          *(const f16x8*)(asrc + ((kk + 2) * 64 + (lane ^ (kk + 2))) * 8);
      f16x8 a3 =
          *(const f16x8*)(asrc + ((kk + 3) * 64 + (lane ^ (kk + 3))) * 8);
      acc0 = __builtin_amdgcn_mfma_f32_16x16x32_f16(a0, bW[kk], acc0, 0, 0, 0);
      acc1 =
          __builtin_amdgcn_mfma_f32_16x16x32_f16(a1, bW[kk + 1], acc1, 0, 0, 0);
      acc2 =
          __builtin_amdgcn_mfma_f32_16x16x32_f16(a2, bW[kk + 2], acc2, 0, 0, 0);
      acc3 =
          __builtin_amdgcn_mfma_f32_16x16x32_f16(a3, bW[kk + 3], acc3, 0, 0, 0);
    }
#pragma unroll
    for (int r = 0; r < 4; ++r)
      gbuf[wave * 272 + (q * 4 + r) * 17 + n16] =
          (acc0[r] + acc1[r]) + (acc2[r] + acc3[r]);
    __syncthreads();

    // ---- Epilogue (fp32) + direct publish (waves 0-1; partner via shfl).
    if (tid < 128) {
      float g0 = gbuf[0 * 272 + eb * 17 + en] + 2.f * bb0;      // i
      float g1 = gbuf[0 * 272 + eb * 17 + en + 8] + 2.f * bb1;  // f
      float g2 = gbuf[1 * 272 + eb * 17 + en] + 2.f * bb2;      // m~
      float g3 = gbuf[1 * 272 + eb * 17 + en + 8] + 2.f * bb3;  // o
      float g4 = gbuf[2 * 272 + eb * 17 + en] + 2.f * bb4;      // hw
      float p5 = gbuf[2 * 272 + eb * 17 + en + 8];              // (x+h)@W5
      float qv = gbuf[3 * 272 + eb * 17 + en];                  // h@W5
      float ig = sigf(g0), fg = sigf(g1), mt = tanhfast(g2);
      float og = sigf(g3), hwv = sigf(g4);
      float pi5 = p5 - qv + bb5;
      float cold = cbuf[tid];
      float mem = ig * mt + fg * cold;
      float o1 = og * tanhfast(mem);
      float ov = hwv * o1 + (1.0f - hwv) * pi5;
      float msk = (t < mylen) ? 1.0f : 0.0f;
      ov *= msk;
      mem *= msk;
      cbuf[tid] = mem;

      unsigned hbits =
          (unsigned)__builtin_bit_cast(unsigned short, (f16)ov);
      unsigned other = (unsigned)__shfl_xor((int)hbits, 1, 64);
      if ((en & 1) == 0) {
        u64 wv = (u64)(hbits & 0xffffu) | ((u64)(other & 0xffffu) << 16) |
                 ((u64)(unsigned)(t + 1) << 32);
        __hip_atomic_store(
            hex + (size_t)((t + 1) & 1) * 4096 + eb * 256 + wg * 4 + (en >> 1),
            wv, __ATOMIC_RELAXED, __HIP_MEMORY_SCOPE_AGENT);
      }
      // Per-wave hint flag: lane 0 of each publishing wave (tid 0 / 64)
      // issues it in program order right after the wave's pair stores.
      if ((tid & 63) == 0)
        __hip_atomic_store(flg + ((size_t)wg * 2 + (tid >> 6)) * 8,
                           (u64)(t + 1), __ATOMIC_RELAXED,
                           __HIP_MEMORY_SCOPE_AGENT);
      // Out store after publish: keep the flag/pair stores at the head of
      // the store queue.
      out[((size_t)eb * TT + t) * HHH + wg * CC + en] = ov;
    }

    // Prefetch x(t+1); latency hides under next step's flag polling.
    if (t + 1 < TT) {
#pragma unroll
      for (int i = 0; i < 8; ++i)
        xv[i] = *(const f32x4*)(x + xcm[i] + (size_t)(t + 1) * DD);
    }
    // No trailing __syncthreads: next-step staging only touches u_sw/h_sw,
    // whose step-t reads all completed before the post-MFMA barrier; gbuf
    // writes for t+1 are fenced by the next post-staging barrier, which
    // cannot be reached before this WG's own publish (tag verify includes
    // own columns).
  }
}

extern "C" void kernel_launch(void* const* d_in, const int* in_sizes, int n_in,
                              void* d_out, int out_size, void* d_ws,
                              size_t ws_size, hipStream_t stream) {
  (void)in_sizes;
  (void)n_in;
  (void)out_size;
  (void)ws_size;
  const float* x = (const float*)d_in[0];
  const int* lengths = (const int*)d_in[1];
  const float* W = (const float*)d_in[2];
  const float* bias = (const float*)d_in[3];
  float* out = (float*)d_out;

  // Workspace: [2][4096] tagged pairs (64 KB) + [128] 64B-strided per-wave
  // flags (8 KB). memset → h0=0, tag=0, flags=0 (t=0 gate passes: 0 >= 0).
  u64* hex = (u64*)d_ws;
  hipMemsetAsync(d_ws, 0, (2 * 4096 + 128 * 8) * sizeof(u64), stream);

  lstm_scan<<<dim3(NG), dim3(BLK), 0, stream>>>(x, lengths, W, bias, out, hex);
}

// Round 2
// 8293.273 us; speedup vs baseline: 1.0232x; 1.0232x over previous
//
#include <hip/hip_runtime.h>

// AugmentedLstm: B=16, T=2048, D=H=512.
// 64 persistent WGs x 256 threads. No grid barrier: h' published as packed
// u64 agent-scope relaxed atomics {2 x f16, u32 step-tag}; consumers poll
// tags. Round 5: revert round-4 flag gate (serial flag->data = +1 IC trip,
// measured +1150cy/step; detection must stay CONCURRENT with data fetch).
// New: (a) ROLE SPLIT — publisher waves 0-1 never poll/stage, so their
// out-store + publish-store acks (vmcnt counts stores!) can't stall the
// poll's s_waitcnt vmcnt(0); waves 2-3 own poll+stage+x-prefetch, each
// thread holding one 4-col k-slice x all 16 rows (single-publisher, 1KB/
// wave coalesced). (b) WIDE POLLS — one global_load_dwordx4 sc0 sc1 per
// 2 u64 (single asm block, trailing vmcnt(0); 16B serviced as one TCC
// access so no intra-u64 tearing; sc0 sc1 keeps lines out of stale L2).
// Tags embedded per-u64 remain the ground truth.
//
// Math: g = (x_t + h)@Wt[:, :5H] + 2b  (pi and ps share W)
//       pi5 = (x+h)@W5 - h@W5 + b5     (highway input)

#define NG 64
#define BLK 256
#define BB 16
#define TT 2048
#define DD 512
#define HHH 512
#define CC 8

typedef _Float16 f16;
typedef _Float16 f16x2 __attribute__((ext_vector_type(2)));
typedef _Float16 f16x4 __attribute__((ext_vector_type(4)));
typedef _Float16 f16x8 __attribute__((ext_vector_type(8)));
typedef float f32x4 __attribute__((ext_vector_type(4)));
typedef unsigned long long u64;
typedef unsigned int u32;
typedef u32 u32x2 __attribute__((ext_vector_type(2)));
typedef u32 u32x4 __attribute__((ext_vector_type(4)));

__device__ __forceinline__ float sigf(float v) {
  return 1.0f / (1.0f + __expf(-v));
}
__device__ __forceinline__ float tanhfast(float v) {
  return 2.0f / (1.0f + __expf(-2.0f * v)) - 1.0f;
}

__global__ __launch_bounds__(BLK, 1) void lstm_scan(
    const float* __restrict__ x, const int* __restrict__ lengths,
    const float* __restrict__ W, const float* __restrict__ bias,
    float* __restrict__ out, u64* __restrict__ hex /* [2][16][256] tagged */) {
  __shared__ f16 u_sw[BB * DD];        // u = x+h, swizzled A-frag order
  __shared__ f16 h_sw[BB * DD];        // h alone (for h@W5)
  __shared__ float gbuf[4 * 16 * 17];  // per-tile MFMA results
  __shared__ float cbuf[BB * CC];      // cell state

  const int tid = threadIdx.x;
  const int wg = blockIdx.x;
  const int wave = tid >> 6;
  const int lane = tid & 63;
  const int q = lane >> 4;
  const int n16 = lane & 15;

  // ---- Weight B-fragments in registers (loaded once, all waves).
  // Tiles 0..2: A=u, 16 cols = gates {0,1},{2,3},{4,5} x 8 cols.
  // Tile  3   : A=h, cols 0..7 = gate-5 rows (h@W5), cols 8..15 zero.
  f16x8 bW[16];
  {
    int grow = 0;
    bool valid = true;
    if (wave < 3) {
      int gate = 2 * wave + (n16 >> 3);
      grow = gate * HHH + wg * CC + (n16 & 7);
    } else if (n16 < 8) {
      grow = 5 * HHH + wg * CC + n16;
    } else {
      valid = false;
    }
    const float* wr = W + (size_t)grow * DD;
#pragma unroll
    for (int kk = 0; kk < 16; ++kk) {
      f16x8 v;
      if (valid) {
        const float* p = wr + kk * 32 + q * 8;
#pragma unroll
        for (int j = 0; j < 8; ++j) v[j] = (f16)p[j];
      } else {
#pragma unroll
        for (int j = 0; j < 8; ++j) v[j] = (f16)0.0f;
      }
      bW[kk] = v;
    }
  }

  // ---- Staging role (waves 2-3 only): ts = tid-128, thread owns the
  // 4-col k-slice k0 = ts*4 across ALL 16 rows (m = chunk index i).
  // LDS granule (8 f16): logical (kk*64 + L), physical (kk*64 + (L^kk)) —
  // XOR swizzle keeps ds_write at the 4-way floor, ds_read_b128 clean.
  // All 16 polled u64 pairs come from ONE publisher WG (wgp = k0>>3).
  int soffv[16];
  const float* bx = nullptr;  // x + b-row base for this thread's k-slice
  int c0 = 0;                 // u64 index of pair 0 within a row
  if (tid >= 128) {
    int ts = tid - 128;
    int k0 = ts * 4;
    c0 = k0 >> 1;
    int kk = k0 >> 5, qq = (k0 >> 3) & 3, j0 = k0 & 7;
#pragma unroll
    for (int i = 0; i < 16; ++i) {
      int L = qq * 16 + i;
      soffv[i] = (kk * 64 + (L ^ kk)) * 8 + j0;
    }
    bx = x + k0;
  }

  // ---- Epilogue constants (threads 0..127: b = tid>>3, n = tid&7).
  const int eb = tid >> 3;
  const int en = tid & 7;
  float bb0 = 0, bb1 = 0, bb2 = 0, bb3 = 0, bb4 = 0, bb5 = 0;
  int mylen = 0;
  if (tid < 128) {
    int gc = wg * CC + en;
    bb0 = bias[0 * HHH + gc];
    bb1 = bias[1 * HHH + gc];
    bb2 = bias[2 * HHH + gc];
    bb3 = bias[3 * HHH + gc];
    bb4 = bias[4 * HHH + gc];
    bb5 = bias[5 * HHH + gc];
    mylen = lengths[eb];
    cbuf[tid] = 0.0f;
  }

  // Prefetch x(t=0) — staging waves only. Row i lives at bx + i*TT*DD.
  f32x4 xv[16];
  if (tid >= 128) {
#pragma unroll
    for (int i = 0; i < 16; ++i)
      xv[i] = *(const f32x4*)(bx + (size_t)i * TT * DD);
  }

  __syncthreads();

  for (int t = 0; t < TT; ++t) {
    if (tid >= 128) {
      // ---- Poll h(t): tag == t in parity slot t&1. Each round re-issues
      // all 8 dwordx4 loads concurrently (one IC round trip per round);
      // the successful round IS the data fetch (no serial flag hop).
      const u64* hb = hex + (size_t)(t & 1) * 4096 + c0;
      const u64* p0 = hb;
      const u64* p1 = hb + 512;
      const u64* p2 = hb + 1024;
      const u64* p3 = hb + 1536;
      const u64* p4 = hb + 2048;
      const u64* p5 = hb + 2560;
      const u64* p6 = hb + 3072;
      const u64* p7 = hb + 3584;
      const u32 wtag = (u32)t;
      u32x4 w0, w1, w2, w3, w4, w5, w6, w7;
      u32x4 w8, w9, w10, w11, w12, w13, w14, w15;
      for (;;) {
        asm volatile(
            "global_load_dwordx4 %0, %16, off sc0 sc1\n\t"
            "global_load_dwordx4 %1, %16, off offset:2048 sc0 sc1\n\t"
            "global_load_dwordx4 %2, %17, off sc0 sc1\n\t"
            "global_load_dwordx4 %3, %17, off offset:2048 sc0 sc1\n\t"
            "global_load_dwordx4 %4, %18, off sc0 sc1\n\t"
            "global_load_dwordx4 %5, %18, off offset:2048 sc0 sc1\n\t"
            "global_load_dwordx4 %6, %19, off sc0 sc1\n\t"
            "global_load_dwordx4 %7, %19, off offset:2048 sc0 sc1\n\t"
            "global_load_dwordx4 %8, %20, off sc0 sc1\n\t"
            "global_load_dwordx4 %9, %20, off offset:2048 sc0 sc1\n\t"
            "global_load_dwordx4 %10, %21, off sc0 sc1\n\t"
            "global_load_dwordx4 %11, %21, off offset:2048 sc0 sc1\n\t"
            "global_load_dwordx4 %12, %22, off sc0 sc1\n\t"
            "global_load_dwordx4 %13, %22, off offset:2048 sc0 sc1\n\t"
            "global_load_dwordx4 %14, %23, off sc0 sc1\n\t"
            "global_load_dwordx4 %15, %23, off offset:2048 sc0 sc1\n\t"
            "s_waitcnt vmcnt(0)"
            : "=v"(w0), "=v"(w1), "=v"(w2), "=v"(w3), "=v"(w4), "=v"(w5),
              "=v"(w6), "=v"(w7), "=v"(w8), "=v"(w9), "=v"(w10), "=v"(w11),
              "=v"(w12), "=v"(w13), "=v"(w14), "=v"(w15)
            : "v"(p0), "v"(p1), "v"(p2), "v"(p3), "v"(p4), "v"(p5), "v"(p6),
              "v"(p7)
            : "memory");
        u32 bad = (w0[1] ^ wtag) | (w0[3] ^ wtag);
        bad |= (w1[1] ^ wtag) | (w1[3] ^ wtag);
        bad |= (w2[1] ^ wtag) | (w2[3] ^ wtag);
        bad |= (w3[1] ^ wtag) | (w3[3] ^ wtag);
        bad |= (w4[1] ^ wtag) | (w4[3] ^ wtag);
        bad |= (w5[1] ^ wtag) | (w5[3] ^ wtag);
        bad |= (w6[1] ^ wtag) | (w6[3] ^ wtag);
        bad |= (w7[1] ^ wtag) | (w7[3] ^ wtag);
        bad |= (w8[1] ^ wtag) | (w8[3] ^ wtag);
        bad |= (w9[1] ^ wtag) | (w9[3] ^ wtag);
        bad |= (w10[1] ^ wtag) | (w10[3] ^ wtag);
        bad |= (w11[1] ^ wtag) | (w11[3] ^ wtag);
        bad |= (w12[1] ^ wtag) | (w12[3] ^ wtag);
        bad |= (w13[1] ^ wtag) | (w13[3] ^ wtag);
        bad |= (w14[1] ^ wtag) | (w14[3] ^ wtag);
        bad |= (w15[1] ^ wtag) | (w15[3] ^ wtag);
        if (bad == 0) break;
      }

      // ---- Stage u = f16(x)+h and h into LDS (swizzled).
#define STG(i, Wv)                                             \
  {                                                            \
    u32x2 hp;                                                  \
    hp[0] = Wv[0];                                             \
    hp[1] = Wv[2];                                             \
    f16x4 hv = __builtin_bit_cast(f16x4, hp);                  \
    f16x4 uv;                                                  \
    uv[0] = (f16)xv[i][0] + hv[0];                             \
    uv[1] = (f16)xv[i][1] + hv[1];                             \
    uv[2] = (f16)xv[i][2] + hv[2];                             \
    uv[3] = (f16)xv[i][3] + hv[3];                             \
    *(f16x4*)(u_sw + soffv[i]) = uv;                           \
    *(f16x4*)(h_sw + soffv[i]) = hv;                           \
  }
      STG(0, w0) STG(1, w1) STG(2, w2) STG(3, w3)
      STG(4, w4) STG(5, w5) STG(6, w6) STG(7, w7)
      STG(8, w8) STG(9, w9) STG(10, w10) STG(11, w11)
      STG(12, w12) STG(13, w13) STG(14, w14) STG(15, w15)
#undef STG

      // Prefetch x(t+1); HBM latency hides under MFMA + next poll (its
      // vmcnt(0) drains these on the first round).
      if (t + 1 < TT) {
#pragma unroll
        for (int i = 0; i < 16; ++i)
          xv[i] = *(const f32x4*)(bx + (size_t)i * TT * DD +
                                  (size_t)(t + 1) * DD);
      }
    }
    __syncthreads();

    // ---- MFMA: wave's 16-col tile, K=512, 4 independent chains.
    f32x4 acc0 = {0.f, 0.f, 0.f, 0.f}, acc1 = {0.f, 0.f, 0.f, 0.f};
    f32x4 acc2 = {0.f, 0.f, 0.f, 0.f}, acc3 = {0.f, 0.f, 0.f, 0.f};
    const f16* asrc = (wave < 3) ? u_sw : h_sw;
#pragma unroll
    for (int kk = 0; kk < 16; kk += 4) {
      f16x8 a0 = *(const f16x8*)(asrc + (kk * 64 + (lane ^ kk)) * 8);
      f16x8 a1 =
          *(const f16x8*)(asrc + ((kk + 1) * 64 + (lane ^ (kk + 1))) * 8);
      f16x8 a2 =
          *(const f16x8*)(asrc + ((kk + 2) * 64 + (lane ^ (kk + 2))) * 8);
      f16x8 a3 =
          *(const f16x8*)(asrc + ((kk + 3) * 64 + (lane ^ (kk + 3))) * 8);
      acc0 = __builtin_amdgcn_mfma_f32_16x16x32_f16(a0, bW[kk], acc0, 0, 0, 0);
      acc1 =
          __builtin_amdgcn_mfma_f32_16x16x32_f16(a1, bW[kk + 1], acc1, 0, 0, 0);
      acc2 =
          __builtin_amdgcn_mfma_f32_16x16x32_f16(a2, bW[kk + 2], acc2, 0, 0, 0);
      acc3 =
          __builtin_amdgcn_mfma_f32_16x16x32_f16(a3, bW[kk + 3], acc3, 0, 0, 0);
    }
#pragma unroll
    for (int r = 0; r < 4; ++r)
      gbuf[wave * 272 + (q * 4 + r) * 17 + n16] =
          (acc0[r] + acc1[r]) + (acc2[r] + acc3[r]);
    __syncthreads();

    // ---- Epilogue (fp32) + direct publish (waves 0-1; partner via shfl).
    if (tid < 128) {
      float g0 = gbuf[0 * 272 + eb * 17 + en] + 2.f * bb0;      // i
      float g1 = gbuf[0 * 272 + eb * 17 + en + 8] + 2.f * bb1;  // f
      float g2 = gbuf[1 * 272 + eb * 17 + en] + 2.f * bb2;      // m~
      float g3 = gbuf[1 * 272 + eb * 17 + en + 8] + 2.f * bb3;  // o
      float g4 = gbuf[2 * 272 + eb * 17 + en] + 2.f * bb4;      // hw
      float p5 = gbuf[2 * 272 + eb * 17 + en + 8];              // (x+h)@W5
      float qv = gbuf[3 * 272 + eb * 17 + en];                  // h@W5
      float ig = sigf(g0), fg = sigf(g1), mt = tanhfast(g2);
      float og = sigf(g3), hwv = sigf(g4);
      float pi5 = p5 - qv + bb5;
      float cold = cbuf[tid];
      float mem = ig * mt + fg * cold;
      float o1 = og * tanhfast(mem);
      float ov = hwv * o1 + (1.0f - hwv) * pi5;
      float msk = (t < mylen) ? 1.0f : 0.0f;
      ov *= msk;
      mem *= msk;
      cbuf[tid] = mem;

      unsigned hbits =
          (unsigned)__builtin_bit_cast(unsigned short, (f16)ov);
      unsigned other = (unsigned)__shfl_xor((int)hbits, 1, 64);
      if ((en & 1) == 0) {
        u64 wv = (u64)(hbits & 0xffffu) | ((u64)(other & 0xffffu) << 16) |
                 ((u64)(unsigned)(t + 1) << 32);
        __hip_atomic_store(
            hex + (size_t)((t + 1) & 1) * 4096 + eb * 256 + wg * 4 + (en >> 1),
            wv, __ATOMIC_RELAXED, __HIP_MEMORY_SCOPE_AGENT);
      }
      // Out store after publish: keep the publish at the head of the
      // store queue. These acks never gate a poll now (role split).
      out[((size_t)eb * TT + t) * HHH + wg * CC + en] = ov;
    }
    // No trailing __syncthreads: next-step staging (waves 2-3) only
    // touches u_sw/h_sw, whose step-t reads all completed before the
    // post-MFMA barrier; gbuf writes for t+1 happen after the next
    // post-staging barrier, which waves 0-1 only reach after this
    // epilogue. Parity-slot reuse (t+2) requires this WG's t+1 publish,
    // which is ordered after staging(t) via the two barriers.
  }
}

extern "C" void kernel_launch(void* const* d_in, const int* in_sizes, int n_in,
                              void* d_out, int out_size, void* d_ws,
                              size_t ws_size, hipStream_t stream) {
  (void)in_sizes;
  (void)n_in;
  (void)out_size;
  (void)ws_size;
  const float* x = (const float*)d_in[0];
  const int* lengths = (const int*)d_in[1];
  const float* W = (const float*)d_in[2];
  const float* bias = (const float*)d_in[3];
  float* out = (float*)d_out;

  u64* hex = (u64*)d_ws;  // [2][16][256] tagged pairs = 64 KB
  hipMemsetAsync(d_ws, 0, 2 * 4096 * sizeof(u64), stream);  // h0=0, tag=0

  lstm_scan<<<dim3(NG), dim3(BLK), 0, stream>>>(x, lengths, W, bias, out, hex);
}